// Round 3
// baseline (779.621 us; speedup 1.0000x reference)
//
#include <hip/hip_runtime.h>

// Problem constants (from reference)
#define B_      128
#define NPIX    32      // N = M = 32
#define NNEO    30      // N-2
#define CSTATE  19      // real state channels
#define CPAD    20      // padded channel stride (16B-aligned pixel blocks)
#define OUTD    21      // OUT_DIM
#define ITERS   10
#define THRESHV 0.0007f

#define STATE_ELEMS_PAD (B_ * NPIX * NPIX * CPAD)  // 2,621,440 floats per buffer
#define NCELLS      (B_ * NNEO * NNEO)             // 115,200
#define CLASS_ELEMS (NCELLS * 3)                   // 345,600

// ---------------------------------------------------------------------------
// init: zero ONLY the borders of both (padded) state buffers. Interior pixels
// are fully written by each step before being read (pad channel 19 is written
// as 0 by the step kernels and never used in arithmetic).
// ---------------------------------------------------------------------------
__global__ void nca_init(float* __restrict__ stateA, float* __restrict__ stateB) {
    int idx = blockIdx.x * blockDim.x + threadIdx.x;
    const int total = B_ * 124 * CPAD;
    if (idx >= total) return;
    int c  = idx % CPAD;
    int t2 = idx / CPAD;
    int cellp = t2 % 124;
    int b    = t2 / 124;
    int i, j;
    if (cellp < 32)      { i = 0;  j = cellp; }
    else if (cellp < 64) { i = 31; j = cellp - 32; }
    else { int k = cellp - 64; i = 1 + (k >> 1); j = (k & 1) ? 31 : 0; }
    size_t off = (((size_t)b * NPIX + i) * NPIX + j) * CPAD + c;
    stateA[off] = 0.0f;
    stateB[off] = 0.0f;
}

// ---------------------------------------------------------------------------
// R13 (= R12 with the token-pasting bug fixed): one thread per cell + DEEP
// LOAD HOISTING.
// R11 failed because the compiler allocated only 48 VGPRs and serialized the
// per-patch loads (each global_load -> wait -> use), exposing L2/HBM latency
// ~27x per step at only 1.76 waves/SIMD of TLP.
// Fix: all 54 loads (9 img scalars + 45 state float4) are hoisted to the top
// of layer 1 as STATICALLY-NAMED values (no runtime-indexed arrays -> no
// scratch), consumed by 9 fully-unrolled patch blocks. All loads in flight on
// vmcnt at once; latency exposed ~once. Weights stay on the wave-uniform
// s_load (lgkmcnt) path and pipeline under the FMA stream.
// NOTE: float4 vars are named f<P><a..e> — a digit directly before ".x" would
// lex as a pp-number and break ## pasting (R12's compile failure).
// MODE: 0 = first step (state==0, perc=identity), 1 = mid, 2 = last.
// ---------------------------------------------------------------------------

#define ROW30(x, wr) do { const float xx_ = (x); \
    const float* __restrict__ wrp_ = (wr); \
    _Pragma("unroll") for (int o_ = 0; o_ < 30; o_++) acc[o_] += xx_ * wrp_[o_]; \
} while (0)

#define LD5(P, OFF) \
    const float4 f##P##a = *(const float4*)(sbase + (OFF)); \
    const float4 f##P##b = *(const float4*)(sbase + (OFF) + 4); \
    const float4 f##P##c = *(const float4*)(sbase + (OFF) + 8); \
    const float4 f##P##d = *(const float4*)(sbase + (OFF) + 12); \
    const float4 f##P##e = *(const float4*)(sbase + (OFF) + 16);

#define PATCH(P, IV) do { \
    const float* __restrict__ wp_ = W1 + (P) * 600; \
    ROW30((IV),      wp_);       \
    ROW30(f##P##a.x, wp_ + 30);  ROW30(f##P##a.y, wp_ + 60);  \
    ROW30(f##P##a.z, wp_ + 90);  ROW30(f##P##a.w, wp_ + 120); \
    ROW30(f##P##b.x, wp_ + 150); ROW30(f##P##b.y, wp_ + 180); \
    ROW30(f##P##b.z, wp_ + 210); ROW30(f##P##b.w, wp_ + 240); \
    ROW30(f##P##c.x, wp_ + 270); ROW30(f##P##c.y, wp_ + 300); \
    ROW30(f##P##c.z, wp_ + 330); ROW30(f##P##c.w, wp_ + 360); \
    ROW30(f##P##d.x, wp_ + 390); ROW30(f##P##d.y, wp_ + 420); \
    ROW30(f##P##d.z, wp_ + 450); ROW30(f##P##d.w, wp_ + 480); \
    ROW30(f##P##e.x, wp_ + 510); ROW30(f##P##e.y, wp_ + 540); \
    ROW30(f##P##e.z, wp_ + 570); \
} while (0)

template<int MODE>
__global__ __launch_bounds__(256, 2)
void nca_cell(const float* __restrict__ img,
              const float* __restrict__ W1, const float* __restrict__ b1,
              const float* __restrict__ W2, const float* __restrict__ b2,
              const float* __restrict__ W3, const float* __restrict__ b3,
              const float* __restrict__ state_old, float* __restrict__ state_new,
              int* __restrict__ perc,
              float* __restrict__ guesses_out, float* __restrict__ class_out)
{
    const int cell = blockIdx.x * 256 + threadIdx.x;   // < NCELLS by construction
    const int b  = cell / (NNEO * NNEO);
    const int ij = cell - b * (NNEO * NNEO);
    const int i  = ij / NNEO;
    const int j  = ij - i * NNEO;

    int px, py;
    if (MODE == 0) { px = i; py = j; }
    else           { px = perc[2 * cell]; py = perc[2 * cell + 1]; }

    const float* __restrict__ ib = img + (size_t)b * (NPIX * NPIX);

    // ---------------- layer 1: 182 -> 30, all 30 in registers -------------
    float acc[30];
#pragma unroll
    for (int o = 0; o < 30; o++) acc[o] = b1[o];

    if (MODE == 0) {
        // state == 0 at t=0: only the 9 image rows contribute
        const float* __restrict__ ibp = ib + px * NPIX + py;
#pragma clang loop unroll(disable)
        for (int pr = 0; pr < 3; pr++) {
#pragma clang loop unroll(disable)
            for (int pc = 0; pc < 3; pc++) {
                const float iv = ibp[pr * NPIX + pc];
                ROW30(iv, W1 + (pr * 3 + pc) * 600);
            }
        }
    } else {
        // ---- hoist ALL loads: 9 img scalars + 45 state float4 ------------
        const float* __restrict__ ibp = ib + px * NPIX + py;
        const float iv0 = ibp[0],  iv1 = ibp[1],  iv2 = ibp[2];
        const float iv3 = ibp[32], iv4 = ibp[33], iv5 = ibp[34];
        const float iv6 = ibp[64], iv7 = ibp[65], iv8 = ibp[66];
        const float* __restrict__ sbase =
            state_old + (((size_t)b * NPIX + i) * NPIX + j) * CPAD;
        LD5(0, 0)    LD5(1, 20)   LD5(2, 40)
        LD5(3, 640)  LD5(4, 660)  LD5(5, 680)
        LD5(6, 1280) LD5(7, 1300) LD5(8, 1320)

        // ---- consume: 9 fully-unrolled patches (5400 FMAs) ---------------
        PATCH(0, iv0); PATCH(1, iv1); PATCH(2, iv2);
        PATCH(3, iv3); PATCH(4, iv4); PATCH(5, iv5);
        PATCH(6, iv6); PATCH(7, iv7); PATCH(8, iv8);
    }
    {
        const float posx = (float)(px - 16) * 0.0625f;
        const float posy = (float)(py - 16) * 0.0625f;
        ROW30(posx, W1 + 180 * 30);
        ROW30(posy, W1 + 181 * 30);
    }

    float a1[30];
#pragma unroll
    for (int o = 0; o < 30; o++) a1[o] = fmaxf(acc[o], 0.0f);

    // ---------------- layer 2: 30 -> 30 -----------------------------------
    float h2[30];
#pragma unroll
    for (int o = 0; o < 30; o++) h2[o] = b2[o];
#pragma unroll
    for (int k = 0; k < 30; k++) {
        const float x = a1[k];
        const float* __restrict__ wr = W2 + k * 30;
#pragma unroll
        for (int o = 0; o < 30; o++) h2[o] += x * wr[o];
    }
#pragma unroll
    for (int o = 0; o < 30; o++) h2[o] = fmaxf(h2[o], 0.0f);

    // ---------------- layer 3: 30 -> 21 -----------------------------------
    float ov[21];
#pragma unroll
    for (int c = 0; c < 21; c++) ov[c] = b3[c];
#pragma unroll
    for (int k = 0; k < 30; k++) {
        const float x = h2[k];
        const float* __restrict__ wr = W3 + k * 21;
#pragma unroll
        for (int c = 0; c < 21; c++) ov[c] += x * wr[c];
    }

    // ---------------- outputs --------------------------------------------
    const size_t coff = (((size_t)b * NPIX + (i + 1)) * NPIX + (j + 1)) * CPAD;
    if (MODE == 2) {
        float* __restrict__ g = guesses_out + (size_t)cell * OUTD;
#pragma unroll
        for (int c = 0; c < 21; c++) g[c] = ov[c];
        const float4 c4 = *(const float4*)(state_old + coff + 16); // ch16..19
        float* __restrict__ cs = class_out + (size_t)cell * 3;
        cs[0] = c4.x + ov[16];
        cs[1] = c4.y + ov[17];
        cs[2] = c4.z + ov[18];
    } else {
        float4* __restrict__ ns4 = (float4*)(state_new + coff);
        if (MODE == 0) {
            ns4[0] = make_float4(ov[0],  ov[1],  ov[2],  ov[3]);
            ns4[1] = make_float4(ov[4],  ov[5],  ov[6],  ov[7]);
            ns4[2] = make_float4(ov[8],  ov[9],  ov[10], ov[11]);
            ns4[3] = make_float4(ov[12], ov[13], ov[14], ov[15]);
            ns4[4] = make_float4(ov[16], ov[17], ov[18], 0.0f);
        } else {
            const float4* __restrict__ cs4 = (const float4*)(state_old + coff);
            const float4 c0 = cs4[0], c1 = cs4[1], c2 = cs4[2], c3 = cs4[3], c4 = cs4[4];
            ns4[0] = make_float4(c0.x + ov[0],  c0.y + ov[1],  c0.z + ov[2],  c0.w + ov[3]);
            ns4[1] = make_float4(c1.x + ov[4],  c1.y + ov[5],  c1.z + ov[6],  c1.w + ov[7]);
            ns4[2] = make_float4(c2.x + ov[8],  c2.y + ov[9],  c2.z + ov[10], c2.w + ov[11]);
            ns4[3] = make_float4(c3.x + ov[12], c3.y + ov[13], c3.z + ov[14], c3.w + ov[15]);
            ns4[4] = make_float4(c4.x + ov[16], c4.y + ov[17], c4.z + ov[18], 0.0f);
        }
        int dxm = (ov[19] > THRESHV) ? 1 : ((ov[19] < -THRESHV) ? -1 : 0);
        int dym = (ov[20] > THRESHV) ? 1 : ((ov[20] < -THRESHV) ? -1 : 0);
        px += dxm; py += dym;
        px = (px < 0) ? 0 : ((px > NNEO - 1) ? NNEO - 1 : px);
        py = (py < 0) ? 0 : ((py > NNEO - 1) ? NNEO - 1 : py);
        perc[2 * cell + 0] = px;
        perc[2 * cell + 1] = py;
    }
}

extern "C" void kernel_launch(void* const* d_in, const int* in_sizes, int n_in,
                              void* d_out, int out_size, void* d_ws, size_t ws_size,
                              hipStream_t stream) {
    const float* img = (const float*)d_in[0];
    const float* W1  = (const float*)d_in[1];
    const float* b1  = (const float*)d_in[2];
    const float* W2  = (const float*)d_in[3];
    const float* b2  = (const float*)d_in[4];
    const float* W3  = (const float*)d_in[5];
    const float* b3  = (const float*)d_in[6];

    float* out = (float*)d_out;
    float* class_out   = out;                 // 345,600 floats
    float* guesses_out = out + CLASS_ELEMS;   // 2,419,200 floats

    float* stateA = (float*)d_ws;
    float* stateB = stateA + STATE_ELEMS_PAD;
    int*   perc   = (int*)(stateB + STATE_ELEMS_PAD);

    {
        const int total = B_ * 124 * CPAD;
        nca_init<<<(total + 255) / 256, 256, 0, stream>>>(stateA, stateB);
    }

    const int grid = NCELLS / 256;            // 450 blocks, exact cover
    // t = 0: state==0, perc = identity; writes stateB + perc
    nca_cell<0><<<grid, 256, 0, stream>>>(img, W1, b1, W2, b2, W3, b3,
                                          stateA, stateB, perc,
                                          guesses_out, class_out);
    // t = 1..8: ping-pong
    for (int t = 1; t < ITERS - 1; t++) {
        const float* so = (t & 1) ? stateB : stateA;
        float*       sn = (t & 1) ? stateA : stateB;
        nca_cell<1><<<grid, 256, 0, stream>>>(img, W1, b1, W2, b2, W3, b3,
                                              so, sn, perc,
                                              guesses_out, class_out);
    }
    // t = 9 (odd): reads stateB, emits guesses + class only
    nca_cell<2><<<grid, 256, 0, stream>>>(img, W1, b1, W2, b2, W3, b3,
                                          stateB, stateA, perc,
                                          guesses_out, class_out);
}

// Round 4
// 336.428 us; speedup vs baseline: 2.3173x; 2.3173x over previous
//
#include <hip/hip_runtime.h>

// Problem constants (from reference)
#define B_      128
#define NPIX    32      // N = M = 32
#define NNEO    30      // N-2
#define CPAD    20      // padded channel stride (16B-aligned pixel blocks)
#define OUTD    21      // OUT_DIM
#define ITERS   10
#define THRESHV 0.0007f
#define HSTRIDE 31      // s_h cell stride: gcd(31,32)=1 -> conflict-free

#define STATE_ELEMS_PAD (B_ * NPIX * NPIX * CPAD)  // 2,621,440 floats per buffer
#define NCELLS      (B_ * NNEO * NNEO)             // 115,200
#define CLASS_ELEMS (NCELLS * 3)                   // 345,600

// ---------------------------------------------------------------------------
// init: zero ONLY the borders of both (padded) state buffers. Interior pixels
// are fully written by each step before being read.
// ---------------------------------------------------------------------------
__global__ void nca_init(float* __restrict__ stateA, float* __restrict__ stateB) {
    int idx = blockIdx.x * blockDim.x + threadIdx.x;
    const int total = B_ * 124 * CPAD;
    if (idx >= total) return;
    int c  = idx % CPAD;
    int t2 = idx / CPAD;
    int cellp = t2 % 124;
    int b    = t2 / 124;
    int i, j;
    if (cellp < 32)      { i = 0;  j = cellp; }
    else if (cellp < 64) { i = 31; j = cellp - 32; }
    else { int k = cellp - 64; i = 1 + (k >> 1); j = (k & 1) ? 31 : 0; }
    size_t off = (((size_t)b * NPIX + i) * NPIX + j) * CPAD + c;
    stateA[off] = 0.0f;
    stateB[off] = 0.0f;
}

// ---------------------------------------------------------------------------
// R14: HALF-SPLIT, LDS-staged, high occupancy.
// Post-mortems: R11 (1 thr/cell, global gather) died on uncoalesced VMEM
// (64 cachelines per fv load instr); R13 (full unroll) died on I-cache
// (~40 KB body). The proven R10 structure (LDS-staged, N-split outputs,
// wave-uniform weight half -> s_load broadcast) was LDS-pipe-bound: fv reads
// duplicated 4x across quarter-threads (~8 of 14 us/CU-step on LDS).
// This version: 2 threads/cell (15 outputs each), 512-thread blocks,
// grid 4x128 = 512 = exactly 2 blocks/CU -> 16 waves/CU.
//   - fv duplication 4x -> 2x; s_h round-trips halve (own 15 stay in regs,
//     only partner's 15 cross through LDS).
//   - rolled patch loops + explicit 20-row unroll (static fv indices, ~1.5 KB
//     body -> I-cache safe).
//   - accumulation order k ascending everywhere (own-reg half and LDS half
//     spliced in order) -> numerics match previous passing versions.
// MODE: 0 = first step (state==0, perc=identity), 1 = mid, 2 = last.
// ---------------------------------------------------------------------------

#define ROW15(A, x, wrp) do { const float xx_ = (x); \
    const float* __restrict__ w_ = (wrp); \
    _Pragma("unroll") for (int o_ = 0; o_ < 15; o_++) (A)[o_] += xx_ * w_[o_]; \
} while (0)

#define ROW12(A, x, wrp) do { const float xx_ = (x); \
    const float* __restrict__ w_ = (wrp); \
    _Pragma("unroll") for (int o_ = 0; o_ < 12; o_++) (A)[o_] += xx_ * w_[o_]; \
} while (0)

#define ROW9(A, x, wrp) do { const float xx_ = (x); \
    const float* __restrict__ w_ = (wrp); \
    _Pragma("unroll") for (int o_ = 0; o_ < 9; o_++) (A)[o_] += xx_ * w_[o_]; \
} while (0)

template<int MODE>
__global__ __launch_bounds__(512, 4)
void nca_step(const float* __restrict__ img,
              const float* __restrict__ W1, const float* __restrict__ b1,
              const float* __restrict__ W2, const float* __restrict__ b2,
              const float* __restrict__ W3, const float* __restrict__ b3,
              const float* __restrict__ state_old, float* __restrict__ state_new,
              int* perc, float* __restrict__ guesses_out,
              float* __restrict__ class_out)
{
    __shared__ float s_state[10 * NPIX * CPAD];   // 25.6 KB (nr+2 <= 10 rows)
    __shared__ float s_img[NPIX * NPIX];          // 4 KB
    __shared__ float s_h[256 * HSTRIDE];          // 31.7 KB   (total 61.3 KB)

    const int b   = blockIdx.y;
    const int rg  = blockIdx.x;                   // 4 groups: rows {8,8,8,6}
    const int i0  = rg * 8;
    const int nr  = (rg == 3) ? 6 : 8;
    const int tid = threadIdx.x;
    const int h   = __builtin_amdgcn_readfirstlane(tid >> 8);  // wave-uniform half
    const int cell = tid & 255;
    const int qoff = h * 15;

    // ---- stage state rows [i0, i0+nr+2) and the image ----------------------
    if (MODE != 0) {
        const int n4 = (nr + 2) * (NPIX * CPAD / 4);   // 1600 or 1280 float4
        const float4* __restrict__ gs4 =
            (const float4*)(state_old + ((size_t)b * NPIX + i0) * (NPIX * CPAD));
        float4* s4 = (float4*)s_state;
        for (int t = tid; t < n4; t += 512) s4[t] = gs4[t];
    }
    if (tid < 256)
        ((float4*)s_img)[tid] = ((const float4*)(img + (size_t)b * NPIX * NPIX))[tid];
    __syncthreads();                                  // B1

    const int cells = nr * NNEO;
    const bool active = cell < cells;

    int r = 0, j = 0, i = 0, gcell = 0, px = 0, py = 0;
    if (active) {
        r = cell / NNEO;
        j = cell - r * NNEO;
        i = i0 + r;
        gcell = (b * NNEO + i) * NNEO + j;
        if (MODE == 0) { px = i; py = j; }
        else           { px = perc[2 * gcell]; py = perc[2 * gcell + 1]; }
    }

    // ---------------- layer 1: 182 -> 30 (this thread: 15 @ qoff) ----------
    float a1[15];
    {
        float acc[15];
#pragma unroll
        for (int o = 0; o < 15; o++) acc[o] = b1[qoff + o];
        if (active) {
            if (MODE == 0) {
#pragma clang loop unroll(disable)
                for (int pr = 0; pr < 3; pr++) {
#pragma clang loop unroll(disable)
                    for (int pc = 0; pc < 3; pc++) {
                        const float iv = s_img[(px + pr) * NPIX + (py + pc)];
                        ROW15(acc, iv, W1 + (pr * 3 + pc) * 600 + qoff);
                    }
                }
            } else {
#pragma clang loop unroll(disable)
                for (int pr = 0; pr < 3; pr++) {
#pragma clang loop unroll(disable)
                    for (int pc = 0; pc < 3; pc++) {
                        const float iv = s_img[(px + pr) * NPIX + (py + pc)];
                        const float* __restrict__ wp = W1 + (pr * 3 + pc) * 600 + qoff;
                        const float4* __restrict__ sp =
                            (const float4*)&s_state[((r + pr) * NPIX + (j + pc)) * CPAD];
                        const float4 ga = sp[0], gb = sp[1], gc = sp[2],
                                     gd = sp[3], ge = sp[4];
                        ROW15(acc, iv,   wp);
                        ROW15(acc, ga.x, wp + 30);  ROW15(acc, ga.y, wp + 60);
                        ROW15(acc, ga.z, wp + 90);  ROW15(acc, ga.w, wp + 120);
                        ROW15(acc, gb.x, wp + 150); ROW15(acc, gb.y, wp + 180);
                        ROW15(acc, gb.z, wp + 210); ROW15(acc, gb.w, wp + 240);
                        ROW15(acc, gc.x, wp + 270); ROW15(acc, gc.y, wp + 300);
                        ROW15(acc, gc.z, wp + 330); ROW15(acc, gc.w, wp + 360);
                        ROW15(acc, gd.x, wp + 390); ROW15(acc, gd.y, wp + 420);
                        ROW15(acc, gd.z, wp + 450); ROW15(acc, gd.w, wp + 480);
                        ROW15(acc, ge.x, wp + 510); ROW15(acc, ge.y, wp + 540);
                        ROW15(acc, ge.z, wp + 570);
                    }
                }
            }
            const float posx = (float)(px - 16) * 0.0625f;
            const float posy = (float)(py - 16) * 0.0625f;
            ROW15(acc, posx, W1 + 180 * 30 + qoff);
            ROW15(acc, posy, W1 + 181 * 30 + qoff);
        }
#pragma unroll
        for (int o = 0; o < 15; o++) a1[o] = fmaxf(acc[o], 0.0f);
        if (active) {
#pragma unroll
            for (int o = 0; o < 15; o++) s_h[cell * HSTRIDE + qoff + o] = a1[o];
        }
    }
    __syncthreads();                                  // B2: a1 visible

    // ---------------- layer 2: 30 -> 30 (this thread: 15 @ qoff) -----------
    float h2[15];
    {
        float acc[15];
#pragma unroll
        for (int o = 0; o < 15; o++) acc[o] = b2[qoff + o];
        if (active) {
            if (h == 0) {
#pragma unroll
                for (int k = 0; k < 15; k++)
                    ROW15(acc, a1[k], W2 + k * 30);
#pragma clang loop unroll(disable)
                for (int k = 15; k < 30; k++) {
                    const float x = s_h[cell * HSTRIDE + k];
                    ROW15(acc, x, W2 + k * 30);
                }
            } else {
#pragma clang loop unroll(disable)
                for (int k = 0; k < 15; k++) {
                    const float x = s_h[cell * HSTRIDE + k];
                    ROW15(acc, x, W2 + k * 30 + 15);
                }
#pragma unroll
                for (int k = 0; k < 15; k++)
                    ROW15(acc, a1[k], W2 + (k + 15) * 30 + 15);
            }
        }
#pragma unroll
        for (int o = 0; o < 15; o++) h2[o] = fmaxf(acc[o], 0.0f);
    }
    __syncthreads();                                  // B3: all a1 reads done
    if (active) {
#pragma unroll
        for (int o = 0; o < 15; o++) s_h[cell * HSTRIDE + qoff + o] = h2[o];
    }
    __syncthreads();                                  // B4: h2 visible

    // ---------------- layer 3: 30 -> 21 (h0: cols 0-11, h1: cols 12-20) ----
    if (active) {
        const size_t coff = (((size_t)b * NPIX + (i + 1)) * NPIX + (j + 1)) * CPAD;
        const int    lc   = ((r + 1) * NPIX + (j + 1)) * CPAD;
        if (h == 0) {
            float ov[12];
#pragma unroll
            for (int c = 0; c < 12; c++) ov[c] = b3[c];
#pragma unroll
            for (int k = 0; k < 15; k++)
                ROW12(ov, h2[k], W3 + k * 21);
#pragma clang loop unroll(disable)
            for (int k = 15; k < 30; k++) {
                const float x = s_h[cell * HSTRIDE + k];
                ROW12(ov, x, W3 + k * 21);
            }
            if (MODE == 2) {
                float* __restrict__ g = guesses_out + (size_t)gcell * OUTD;
#pragma unroll
                for (int c = 0; c < 12; c++) g[c] = ov[c];
            } else {
                float4* __restrict__ ns4 = (float4*)(state_new + coff);
                if (MODE == 0) {
                    ns4[0] = make_float4(ov[0], ov[1], ov[2],  ov[3]);
                    ns4[1] = make_float4(ov[4], ov[5], ov[6],  ov[7]);
                    ns4[2] = make_float4(ov[8], ov[9], ov[10], ov[11]);
                } else {
                    const float4* __restrict__ cs4 = (const float4*)&s_state[lc];
                    const float4 c0 = cs4[0], c1 = cs4[1], c2 = cs4[2];
                    ns4[0] = make_float4(c0.x + ov[0], c0.y + ov[1],
                                         c0.z + ov[2], c0.w + ov[3]);
                    ns4[1] = make_float4(c1.x + ov[4], c1.y + ov[5],
                                         c1.z + ov[6], c1.w + ov[7]);
                    ns4[2] = make_float4(c2.x + ov[8], c2.y + ov[9],
                                         c2.z + ov[10], c2.w + ov[11]);
                }
            }
        } else {
            float ov[9];                              // global cols 12..20
#pragma unroll
            for (int c = 0; c < 9; c++) ov[c] = b3[12 + c];
#pragma clang loop unroll(disable)
            for (int k = 0; k < 15; k++) {
                const float x = s_h[cell * HSTRIDE + k];
                ROW9(ov, x, W3 + k * 21 + 12);
            }
#pragma unroll
            for (int k = 0; k < 15; k++)
                ROW9(ov, h2[k], W3 + (k + 15) * 21 + 12);
            if (MODE == 2) {
                float* __restrict__ g = guesses_out + (size_t)gcell * OUTD;
#pragma unroll
                for (int c = 0; c < 9; c++) g[12 + c] = ov[c];
                const float4 c4 = *(const float4*)&s_state[lc + 16]; // ch16..19
                float* __restrict__ cs = class_out + (size_t)gcell * 3;
                cs[0] = c4.x + ov[4];   // global ov16
                cs[1] = c4.y + ov[5];   // global ov17
                cs[2] = c4.z + ov[6];   // global ov18
            } else {
                float4* __restrict__ ns4 = (float4*)(state_new + coff);
                if (MODE == 0) {
                    ns4[3] = make_float4(ov[0], ov[1], ov[2], ov[3]);
                    ns4[4] = make_float4(ov[4], ov[5], ov[6], 0.0f);
                } else {
                    const float4 c3 = *(const float4*)&s_state[lc + 12];
                    const float4 c4 = *(const float4*)&s_state[lc + 16];
                    ns4[3] = make_float4(c3.x + ov[0], c3.y + ov[1],
                                         c3.z + ov[2], c3.w + ov[3]);
                    ns4[4] = make_float4(c4.x + ov[4], c4.y + ov[5],
                                         c4.z + ov[6], 0.0f);
                }
                int dxm = (ov[7] > THRESHV) ? 1 : ((ov[7] < -THRESHV) ? -1 : 0);
                int dym = (ov[8] > THRESHV) ? 1 : ((ov[8] < -THRESHV) ? -1 : 0);
                px += dxm; py += dym;
                px = (px < 0) ? 0 : ((px > NNEO - 1) ? NNEO - 1 : px);
                py = (py < 0) ? 0 : ((py > NNEO - 1) ? NNEO - 1 : py);
                perc[2 * gcell + 0] = px;
                perc[2 * gcell + 1] = py;
            }
        }
    }
}

extern "C" void kernel_launch(void* const* d_in, const int* in_sizes, int n_in,
                              void* d_out, int out_size, void* d_ws, size_t ws_size,
                              hipStream_t stream) {
    const float* img = (const float*)d_in[0];
    const float* W1  = (const float*)d_in[1];
    const float* b1  = (const float*)d_in[2];
    const float* W2  = (const float*)d_in[3];
    const float* b2  = (const float*)d_in[4];
    const float* W3  = (const float*)d_in[5];
    const float* b3  = (const float*)d_in[6];

    float* out = (float*)d_out;
    float* class_out   = out;                 // 345,600 floats
    float* guesses_out = out + CLASS_ELEMS;   // 2,419,200 floats

    float* stateA = (float*)d_ws;
    float* stateB = stateA + STATE_ELEMS_PAD;
    int*   perc   = (int*)(stateB + STATE_ELEMS_PAD);

    {
        const int total = B_ * 124 * CPAD;
        nca_init<<<(total + 255) / 256, 256, 0, stream>>>(stateA, stateB);
    }

    const dim3 grid(4, B_);                   // 512 blocks = 2/CU exactly
    // t = 0: state==0, perc = identity; writes stateB + perc
    nca_step<0><<<grid, 512, 0, stream>>>(img, W1, b1, W2, b2, W3, b3,
                                          stateA, stateB, perc,
                                          guesses_out, class_out);
    // t = 1..8: ping-pong
    for (int t = 1; t < ITERS - 1; t++) {
        const float* so = (t & 1) ? stateB : stateA;
        float*       sn = (t & 1) ? stateA : stateB;
        nca_step<1><<<grid, 512, 0, stream>>>(img, W1, b1, W2, b2, W3, b3,
                                              so, sn, perc,
                                              guesses_out, class_out);
    }
    // t = 9 (odd): reads stateB, emits guesses + class only
    nca_step<2><<<grid, 512, 0, stream>>>(img, W1, b1, W2, b2, W3, b3,
                                          stateB, stateA, perc,
                                          guesses_out, class_out);
}